// Round 6
// baseline (763.377 us; speedup 1.0000x reference)
//
#include <hip/hip_runtime.h>
#include <hip/hip_bf16.h>
#include <stdint.h>

// B, L, V, D, NCTX, DEPTH, VD = (4096, 77, 49408, 512, 4, 9, 768)
#define BB   4096
#define LL   77
#define DD   512
#define NCTX 4
#define KK   8          // DEPTH - 1
#define VD   768

// Output layout (flat f32 element offsets, concatenated in return order):
// pe (B,L,D) | pt (B,L) | ctx (4,512) | proj_ctx (4,768) | cpt (8,4,512) | vdp (8,4,768)
#define OFF_PE   0L
#define OFF_PT   161480704L   // B*L*D
#define OFF_CTX  161796096L   // + B*L
#define OFF_PROJ 161798144L   // + 2048
#define OFF_CPT  161801216L   // + 3072
#define OFF_VDP  161817600L   // + 16384

typedef float f32x4 __attribute__((ext_vector_type(4)));

// Block-range partition: [0,BB) row-gather | [BB, BB+DOT_BLOCKS) dots | copies
#define DOT_BLOCKS 6912       // 27648 waves, one output elem each
#define CPY_BLOCKS 18         // 4608 float4 (ctx 512 + cpt 4096)
#define ROW_F4     (LL * DD / 4)   // 9856 float4 per text row

__global__ __launch_bounds__(256) void k_main(const int* __restrict__ text,
                                              const float* __restrict__ emb,
                                              const float* __restrict__ ctx,
                                              const float* __restrict__ proj_w,
                                              const float* __restrict__ proj_b,
                                              const float* __restrict__ cpt,
                                              const float* __restrict__ cw,
                                              const float* __restrict__ cb,
                                              float* __restrict__ out) {
    int blk = blockIdx.x;
    int tid = threadIdx.x;

    if (blk < BB) {
        // ================= row gather: one block per text row =================
        __shared__ uintptr_t srcp[LL];   // per-position source row pointer
        __shared__ int smax;
        const int* t = text + blk * LL;

        // wave 0: row max (= eot token, since eot = text[argmax] = max)
        if (tid < 64) {
            int v0 = (tid < LL) ? t[tid] : 0;
            int v1 = (tid + 64 < LL) ? t[tid + 64] : 0;
            int m = v0 > v1 ? v0 : v1;
            #pragma unroll
            for (int off = 32; off; off >>= 1) {
                int o = __shfl_xor(m, off);
                m = o > m ? o : m;
            }
            if (tid == 0) smax = m;
        }
        __syncthreads();

        // threads 0..76: token + source pointer per position; write pt (f32)
        if (tid < LL) {
            int v;
            if (tid == 0)           v = t[0];
            else if (tid <= NCTX)   v = 0;
            else if (tid == LL - 1) { int x = t[LL - 5]; v = (x != 0) ? smax : 0; }
            else                    v = t[tid - NCTX];

            const float* s;
            if (tid >= 1 && tid <= NCTX) s = ctx + (tid - 1) * DD;
            else                         s = emb + (long)v * DD;
            srcp[tid] = (uintptr_t)s;
            out[OFF_PT + (long)blk * LL + tid] = (float)v;
        }
        __syncthreads();

        // stream the 77*512-float slab: 9856 float4, grid-stride by 256
        f32x4* dst = (f32x4*)out + (long)blk * ROW_F4;   // OFF_PE == 0
        #pragma unroll 4
        for (int i = tid; i < ROW_F4; i += 256) {
            int p = i >> 7;          // position (128 f4 per position)
            int c = i & 127;
            const f32x4* s = (const f32x4*)srcp[p];
            __builtin_nontemporal_store(s[c], dst + i);
        }

    } else if (blk < BB + DOT_BLOCKS) {
        // ================= small dots: one wave64 per output element ==========
        int gid  = (blk - BB) * 256 + tid;
        int wave = gid >> 6;
        int lane = gid & 63;

        const float* a;
        const float* b;
        float bias;
        float* dst;

        if (wave < NCTX * VD) {
            int n = wave / VD;
            int o = wave - n * VD;
            a    = ctx + n * DD;
            b    = proj_w + (long)o * DD;
            bias = proj_b[o];
            dst  = out + OFF_PROJ + wave;
        } else {
            int w = wave - NCTX * VD;
            int k = w / (NCTX * VD);
            int r = w - k * (NCTX * VD);
            int n = r / VD;
            int o = r - n * VD;
            a    = cpt + (long)(k * NCTX + n) * DD;
            b    = cw + (long)(k * VD + o) * DD;
            bias = cb[k * VD + o];
            dst  = out + OFF_VDP + w;
        }

        const f32x4* a4 = (const f32x4*)a + lane * 2;
        const f32x4* b4 = (const f32x4*)b + lane * 2;
        f32x4 x0 = a4[0], x1 = a4[1];
        f32x4 y0 = b4[0], y1 = b4[1];
        float s = x0.x * y0.x + x0.y * y0.y + x0.z * y0.z + x0.w * y0.w
                + x1.x * y1.x + x1.y * y1.y + x1.z * y1.z + x1.w * y1.w;
        #pragma unroll
        for (int off = 32; off; off >>= 1) s += __shfl_xor(s, off);
        if (lane == 0) *dst = s + bias;

    } else {
        // ================= pass-through copies ===============================
        int i = (blk - BB - DOT_BLOCKS) * 256 + tid;   // [0, 4608)
        const f32x4* c4 = (const f32x4*)ctx;
        const f32x4* p4 = (const f32x4*)cpt;
        f32x4* o4 = (f32x4*)out;
        if (i < 512) {
            o4[OFF_CTX / 4 + i] = c4[i];
        } else {
            o4[OFF_CPT / 4 + (i - 512)] = p4[i - 512];
        }
    }
}

extern "C" void kernel_launch(void* const* d_in, const int* in_sizes, int n_in,
                              void* d_out, int out_size, void* d_ws, size_t ws_size,
                              hipStream_t stream) {
    const int*   text   = (const int*)d_in[0];
    const float* emb    = (const float*)d_in[1];
    const float* ctx    = (const float*)d_in[2];
    const float* proj_w = (const float*)d_in[3];
    const float* proj_b = (const float*)d_in[4];
    const float* cpt    = (const float*)d_in[5];
    const float* cw     = (const float*)d_in[6];
    const float* cb     = (const float*)d_in[7];
    float* out = (float*)d_out;

    k_main<<<BB + DOT_BLOCKS + CPY_BLOCKS, 256, 0, stream>>>(
        text, emb, ctx, proj_w, proj_b, cpt, cw, cb, out);
}